// Round 5
// baseline (315.003 us; speedup 1.0000x reference)
//
#include <hip/hip_runtime.h>

#define BB 4
#define NN 10000
#define MM 10000
#define PP 128
#define KS 32
#define KSC 4
#define ZZ 128

// workspace layout in floats (all offsets 16B-aligned)
#define OFF_PN 0                       // packed noisy  [B][N][4] (x,y,z,|p|^2)
#define OFF_PC (OFF_PN + BB*NN*4)      // packed clean  [B][M][4] (x,y,z,-|c|^2/2)
#define OFF_FO (OFF_PC + BB*MM*4)      // f_origin      [B][P][4]
#define OFF_ZP (OFF_FO + BB*PP*4)      // zpart         [B][P][128]
#define OFF_FP (OFF_ZP + BB*PP*ZZ)     // f points      [B][P][K][4]
#define OFF_GS (OFF_FP + BB*PP*KS*4)   // ground score  [B][P][K][4]
#define OFF_AC (OFF_GS + BB*PP*KS*4)   // loss accumulator [1]

#define FINF 1e30f

// ---------------- Stage 1: pack points; zero accumulator -----------------------
__global__ void k_pack(const float* __restrict__ noisy, const float* __restrict__ clean,
                       float* __restrict__ ws) {
    int t = blockIdx.x * blockDim.x + threadIdx.x;
    if (t == 0) ws[OFF_AC] = 0.0f;
    const int total = BB*NN + BB*MM;
    if (t >= total) return;
    if (t < BB*NN) {
        float x = noisy[t*3+0], y = noisy[t*3+1], z = noisy[t*3+2];
        float w = (x*x + y*y) + z*z;
        ((float4*)(ws + OFF_PN))[t] = make_float4(x, y, z, w);
    } else {
        int u = t - BB*NN;
        float x = clean[u*3+0], y = clean[u*3+1], z = clean[u*3+2];
        float w = -0.5f * ((x*x + y*y) + z*z);
        ((float4*)(ws + OFF_PC))[u] = make_float4(x, y, z, w);
    }
}

// ---------------- Stage 2: per sampled point: f_origin, feat MLP, zpart --------
__global__ void k_feat(const int* __restrict__ sidx,
                       const float* __restrict__ Wf1, const float* __restrict__ bf1,
                       const float* __restrict__ Wf2, const float* __restrict__ bf2,
                       const float* __restrict__ Ws1, const float* __restrict__ bs1,
                       float* __restrict__ ws) {
    int wave = (blockIdx.x * blockDim.x + threadIdx.x) >> 6;
    int lane = threadIdx.x & 63;
    if (wave >= BB*PP) return;
    int b = wave / PP, p = wave % PP;
    int si = sidx[p];
    float4 q = ((const float4*)(ws + OFF_PN))[b*NN + si];
    if (lane == 0) ((float4*)(ws + OFF_FO))[wave] = q;
    float h = bf1[lane];
    h = fmaf(q.x, Wf1[0*64 + lane], h);
    h = fmaf(q.y, Wf1[1*64 + lane], h);
    h = fmaf(q.z, Wf1[2*64 + lane], h);
    h = fmaxf(h, 0.0f);
    float fa = bf2[lane], fb = bf2[64 + lane];
    for (int i = 0; i < 64; ++i) {
        float hi = __shfl(h, i);
        fa = fmaf(hi, Wf2[i*ZZ + lane],      fa);
        fb = fmaf(hi, Wf2[i*ZZ + 64 + lane], fb);
    }
    float za = bs1[lane], zb = bs1[64 + lane];
    for (int i = 0; i < 64; ++i) {
        float va = __shfl(fa, i);
        float vb = __shfl(fb, i);
        za = fmaf(va, Ws1[(3 + i)*128 + lane],       za);
        zb = fmaf(va, Ws1[(3 + i)*128 + 64 + lane],  zb);
        za = fmaf(vb, Ws1[(67 + i)*128 + lane],      za);
        zb = fmaf(vb, Ws1[(67 + i)*128 + 64 + lane], zb);
    }
    ws[OFF_ZP + wave*ZZ + lane]      = za;
    ws[OFF_ZP + wave*ZZ + 64 + lane] = zb;
}

// ---------------- Stage 3: knn1 — wave-per-query, barrier-free -----------------
// 128 blocks x 256 thr = 512 independent waves. Per wave: (1) strided scan with
// per-lane branchless top-2 min; (2) tau = 32nd smallest of the 128 pooled values
// (in-wave shfl extraction; pool subset => tau >= true d_(32), multi-pop ties
// only loosen -> safe); (3) gated re-scan collects candidates d<=tau to LDS;
// (4) exact (d,idx)-lex rank-select, write FP at reference rank order.
#define CAP1 192
__global__ __launch_bounds__(256) void k_knn1(const int* __restrict__ sidx, float* __restrict__ ws) {
    __shared__ float cd[4][CAP1];
    __shared__ int   ci[4][CAP1];
    __shared__ int   wcnt[4];
    int tid = threadIdx.x;
    int w = tid >> 6, lane = tid & 63;
    int wid = blockIdx.x * 4 + w;        // query id in [0, 512)
    int b = wid >> 7, p = wid & 127;
    const float4* pts = ((const float4*)(ws + OFF_PN)) + b*NN;
    int si = sidx[p];
    float4 q = pts[si];
    if (lane == 0) wcnt[w] = 0;
    // pass 1: per-lane top-2 min (branchless)
    float t0 = FINF, t1 = FINF;
    for (int j = lane; j < NN; j += 64) {
        float4 r = pts[j];
        float dot = fmaf(q.z, r.z, fmaf(q.y, r.y, q.x*r.x));
        float d = fmaf(dot, -2.0f, q.w + r.w);
        t1 = fminf(t1, fmaxf(t0, d));
        t0 = fminf(t0, d);
    }
    // tau = 32nd smallest of pooled 128 values
    float m = 0.0f;
    for (int r = 0; r < KS; ++r) {
        m = t0;
        m = fminf(m, __shfl_xor(m, 1));
        m = fminf(m, __shfl_xor(m, 2));
        m = fminf(m, __shfl_xor(m, 4));
        m = fminf(m, __shfl_xor(m, 8));
        m = fminf(m, __shfl_xor(m, 16));
        m = fminf(m, __shfl_xor(m, 32));
        if (t0 == m) { t0 = t1; t1 = FINF; }
    }
    float tau = m;
    // pass 2: gated collect (recompute d: identical op tree -> bit-identical)
    for (int j = lane; j < NN; j += 64) {
        float4 r = pts[j];
        float dot = fmaf(q.z, r.z, fmaf(q.y, r.y, q.x*r.x));
        float d = fmaf(dot, -2.0f, q.w + r.w);
        if (d <= tau) {
            int pos = atomicAdd(&wcnt[w], 1);
            if (pos < CAP1) { cd[w][pos] = d; ci[w][pos] = j; }
        }
    }
    int C = wcnt[w]; if (C > CAP1) C = CAP1;   // C>=32 guaranteed; random data C~40-80
    // pass 3: exact lex top-32 by rank counting
    for (int i = lane; i < C; i += 64) {
        float di = cd[w][i]; int ii = ci[w][i];
        int rank = 0;
        for (int j2 = 0; j2 < C; ++j2) {
            float dj = cd[w][j2]; int ij = ci[w][j2];
            rank += ((dj < di) || (dj == di && ij < ii)) ? 1 : 0;
        }
        if (rank < KS) ((float4*)(ws + OFF_FP))[wid*KS + rank] = pts[ii];
    }
}

// ---------------- Stage 4: knn2 — shared-query split-stream, tau-gated ---------
// 512 blocks x 256 thr. Block owns 32 queries; ALL 4 waves share them and split
// the M-stream (wave w scans [500w,500w+500) of each 2000-pt LDS chunk).
// Lane = 8 pt-slots x 8 query-groups; thread holds Q=4 queries -> one
// ds_read_b128 serves 256 pair-evals. e = dot - |c|^2/2 (max-e == min-d).
#define CHK2 2000
#define QPB 32
__global__ __launch_bounds__(256) void k_knn2(float* __restrict__ ws) {
    __shared__ float4 sp[2][CHK2];
    __shared__ float  sV[QPB*16];
    __shared__ int    sI[QPB*16];
    __shared__ float  sTau[QPB];
    int tid  = threadIdx.x;
    int w    = tid >> 6;
    int lane = tid & 63;
    int sub  = lane & 7;
    int qg   = lane >> 3;
    int qbase = blockIdx.x * QPB;
    int b = qbase >> 12;                 // 32 | 4096 -> uniform per block
    const float4* pts = ((const float4*)(ws + OFF_PC)) + b*MM;
    float fx[4], fy[4], fz[4];
    #pragma unroll
    for (int c = 0; c < 4; ++c) {
        float4 f4 = ((const float4*)(ws + OFF_FP))[qbase + qg*4 + c];
        fx[c] = f4.x; fy[c] = f4.y; fz[c] = f4.z;
    }
    int sbase = 500 * w;

    auto stage = [&](int buf, int chunk) {
        for (int u = tid; u < CHK2; u += 256) sp[buf][u] = pts[chunk*CHK2 + u];
    };

    stage(0, 0);
    __syncthreads();
    stage(1, 1);                         // loads in flight during phase A

    // ---- phase A: branchless value-only top-4 over wave's slice of chunk 0 ----
    float a0[4], a1[4], a2[4], a3[4];
    #pragma unroll
    for (int c = 0; c < 4; ++c) { a0[c]=-FINF; a1[c]=-FINF; a2[c]=-FINF; a3[c]=-FINF; }
    {
        auto upd = [&](float4 r) {
            #pragma unroll
            for (int c = 0; c < 4; ++c) {
                float e = fmaf(fz[c], r.z, fmaf(fy[c], r.y, fmaf(fx[c], r.x, r.w)));
                a3[c] = fmaxf(a3[c], fminf(a2[c], e));   // bottom-up, old uppers
                a2[c] = fmaxf(a2[c], fminf(a1[c], e));
                a1[c] = fmaxf(a1[c], fminf(a0[c], e));
                a0[c] = fmaxf(a0[c], e);
            }
        };
        for (int t = 0; t < 62; ++t) upd(sp[0][sbase + t*8 + sub]);
        if (sub < 4) upd(sp[0][sbase + 496 + sub]);
    }
    // sub-merge values (multi-pop on ties only loosens tau -> safe)
    #pragma unroll
    for (int c = 0; c < 4; ++c) {
        float h0=a0[c], h1=a1[c], h2=a2[c], h3=a3[c];
        float m0=0.f, m1=0.f, m2=0.f, m3=0.f;
        #pragma unroll
        for (int r = 0; r < 4; ++r) {
            float m = h0;
            m = fmaxf(m, __shfl_xor(m, 1));
            m = fmaxf(m, __shfl_xor(m, 2));
            m = fmaxf(m, __shfl_xor(m, 4));
            if (h0 == m) { h0=h1; h1=h2; h2=h3; h3=-FINF; }
            if (r==0) m0=m; else if (r==1) m1=m; else if (r==2) m2=m; else m3=m;
        }
        float mv = (sub==0)?m0:(sub==1)?m1:(sub==2)?m2:m3;
        if (sub < 4) sV[(qg*4 + c)*16 + w*4 + sub] = mv;
    }
    __syncthreads();                     // sV ready AND chunk 1 staged
    if (tid < QPB) {
        float b0=-FINF,b1=-FINF,b2=-FINF,b3=-FINF;
        #pragma unroll
        for (int u = 0; u < 16; ++u) {
            float v = sV[tid*16 + u];
            b3 = fmaxf(b3, fminf(b2, v));
            b2 = fmaxf(b2, fminf(b1, v));
            b1 = fmaxf(b1, fminf(b0, v));
            b0 = fmaxf(b0, v);
        }
        sTau[tid] = b3;                  // 4th best of full 2000-pt sample
    }
    __syncthreads();
    float tau[4], cut[4];
    #pragma unroll
    for (int c = 0; c < 4; ++c) { tau[c] = sTau[qg*4 + c]; cut[c] = tau[c]; }
    float cmin = fminf(fminf(cut[0],cut[1]), fminf(cut[2],cut[3]));

    // ---- phase B: gated exact scan of all 5 chunks ----
    float e0[4], e1[4], e2[4], e3[4];
    int   i0[4], i1[4], i2[4], i3[4];
    #pragma unroll
    for (int c = 0; c < 4; ++c) { e0[c]=-FINF; e1[c]=-FINF; e2[c]=-FINF; e3[c]=-FINF;
                                  i0[c]=-1; i1[c]=-1; i2[c]=-1; i3[c]=-1; }
    auto scanPt = [&](float4 r, int gidx) {
        float ev[4];
        #pragma unroll
        for (int c = 0; c < 4; ++c)
            ev[c] = fmaf(fz[c], r.z, fmaf(fy[c], r.y, fmaf(fx[c], r.x, r.w)));
        float mx = fmaxf(fmaxf(ev[0],ev[1]), fmaxf(ev[2],ev[3]));
        if (mx >= cmin) {
            #pragma unroll
            for (int c = 0; c < 4; ++c) {
                if (ev[c] >= cut[c]) {           // >= keeps tau-ties (exactness)
                    float e = ev[c];
                    if (e > e3[c]) {             // strict: ascending idx per thread
                        if (e > e1[c]) {
                            e3[c]=e2[c]; i3[c]=i2[c]; e2[c]=e1[c]; i2[c]=i1[c];
                            if (e > e0[c]) { e1[c]=e0[c]; i1[c]=i0[c]; e0[c]=e; i0[c]=gidx; }
                            else           { e1[c]=e; i1[c]=gidx; }
                        } else {
                            if (e > e2[c]) { e3[c]=e2[c]; i3[c]=i2[c]; e2[c]=e; i2[c]=gidx; }
                            else           { e3[c]=e; i3[c]=gidx; }
                        }
                        cut[c] = fmaxf(tau[c], e3[c]);
                        cmin = fminf(fminf(cut[0],cut[1]), fminf(cut[2],cut[3]));
                    }
                }
            }
        }
    };
    auto scanChunk = [&](int buf, int base) {
        for (int t = 0; t < 62; ++t) {
            int loc = sbase + t*8 + sub;
            scanPt(sp[buf][loc], base + loc);
        }
        if (sub < 4) { int loc = sbase + 496 + sub; scanPt(sp[buf][loc], base + loc); }
    };

    scanChunk(0, 0);
    __syncthreads();
    stage(0, 2); scanChunk(1, CHK2);
    __syncthreads();
    stage(1, 3); scanChunk(0, 2*CHK2);
    __syncthreads();
    stage(0, 4); scanChunk(1, 3*CHK2);
    __syncthreads();
    scanChunk(0, 4*CHK2);

    // ---- in-wave merge per query (8 subs), (e desc, idx asc)-lex ----
    #pragma unroll
    for (int c = 0; c < 4; ++c) {
        float we0=0.f, we1=0.f, we2=0.f, we3=0.f;
        int   wi0=0,   wi1=0,   wi2=0,   wi3=0;
        #pragma unroll
        for (int r = 0; r < 4; ++r) {
            float bk = e0[c]; int bi = i0[c]; int bl = lane;
            #pragma unroll
            for (int off = 1; off < 8; off <<= 1) {
                float ok = __shfl_xor(bk, off);
                int   oi = __shfl_xor(bi, off);
                int   ol = __shfl_xor(bl, off);
                if (ok > bk || (ok == bk && oi < bi)) { bk = ok; bi = oi; bl = ol; }
            }
            if (r==0) { we0=bk; wi0=bi; } else if (r==1) { we1=bk; wi1=bi; }
            else if (r==2) { we2=bk; wi2=bi; } else { we3=bk; wi3=bi; }
            if (lane == bl) { e0[c]=e1[c]; i0[c]=i1[c]; e1[c]=e2[c]; i1[c]=i2[c];
                              e2[c]=e3[c]; i2[c]=i3[c]; e3[c]=-FINF; i3[c]=-1; }
        }
        float mv  = (sub==0)?we0:(sub==1)?we1:(sub==2)?we2:we3;
        int   miv = (sub==0)?wi0:(sub==1)?wi1:(sub==2)?wi2:wi3;
        if (sub < 4) { sV[(qg*4+c)*16 + w*4 + sub] = mv; sI[(qg*4+c)*16 + w*4 + sub] = miv; }
    }
    __syncthreads();
    // ---- final per-query merge of 16 candidates + ground score ----
    if (tid < QPB) {
        int q = qbase + tid;
        float4 f4 = ((const float4*)(ws + OFF_FP))[q];
        float b0=-FINF,b1=-FINF,b2=-FINF,b3=-FINF;
        int   j0=-1, j1=-1, j2=-1, j3=-1;
        #pragma unroll
        for (int u = 0; u < 16; ++u) {
            float e = sV[tid*16 + u]; int ii = sI[tid*16 + u];
            bool l3 = (e > b3) || (e == b3 && ii < j3);
            if (l3) {
                bool l2 = (e > b2) || (e == b2 && ii < j2);
                if (l2) {
                    b3=b2; j3=j2;
                    bool l1 = (e > b1) || (e == b1 && ii < j1);
                    if (l1) {
                        b2=b1; j2=j1;
                        bool l0 = (e > b0) || (e == b0 && ii < j0);
                        if (l0) { b1=b0; j1=j0; b0=e; j0=ii; }
                        else    { b1=e; j1=ii; }
                    } else { b2=e; j2=ii; }
                } else { b3=e; j3=ii; }
            }
        }
        float4 n0 = pts[j0], n1 = pts[j1], n2 = pts[j2], n3 = pts[j3];
        float gx = 0.f, gy = 0.f, gz = 0.f;
        gx += n0.x - f4.x; gy += n0.y - f4.y; gz += n0.z - f4.z;
        gx += n1.x - f4.x; gy += n1.y - f4.y; gz += n1.z - f4.z;
        gx += n2.x - f4.x; gy += n2.y - f4.y; gz += n2.z - f4.z;
        gx += n3.x - f4.x; gy += n3.y - f4.y; gz += n3.z - f4.z;
        float* gsp = ws + OFF_GS + (size_t)q*4;
        gsp[0] = gx*0.25f; gsp[1] = gy*0.25f; gsp[2] = gz*0.25f;
    }
}

// ---------------- Stage 5: score MLP + loss — 4-wave j-split -------------------
// 256 blocks x 256 thr; lane = point (64/block), wave w owns j in [16w,16w+16).
__global__ __launch_bounds__(256) void k_mlp(const float* __restrict__ Ws1,
                                             const float* __restrict__ Ws2, const float* __restrict__ bs2,
                                             const float* __restrict__ Ws3, const float* __restrict__ bs3,
                                             float* __restrict__ ws) {
    __shared__ float  sW1[3][128];
    __shared__ float4 sW2[128][16];
    __shared__ float  sB2[64];
    __shared__ float  sW3[64][3];
    __shared__ float  sB3[3];
    __shared__ float  sZP[2][128];
    __shared__ float  sE[3][4][64];
    int tid = threadIdx.x;
    int w = tid >> 6, lane = tid & 63;
    for (int u = tid; u < 384; u += 256) sW1[u >> 7][u & 127] = Ws1[u];
    for (int u = tid; u < 2048; u += 256) ((float4*)sW2)[u] = ((const float4*)Ws2)[u];
    if (tid < 64) sB2[tid] = bs2[tid];
    if (tid < 192) ((float*)sW3)[tid] = Ws3[tid];
    if (tid < 3) sB3[tid] = bs3[tid];
    if (tid < 256) sZP[tid >> 7][tid & 127] = ws[OFF_ZP + (blockIdx.x*2 + (tid >> 7))*ZZ + (tid & 127)];
    __syncthreads();

    int g = blockIdx.x*64 + lane;
    float4 f4 = ((const float4*)(ws + OFF_FP))[g];
    float4 fo = ((const float4*)(ws + OFF_FO))[g >> 5];
    float x0 = f4.x - fo.x, x1 = f4.y - fo.y, x2 = f4.z - fo.z;
    const float* zp = sZP[lane >> 5];

    float4 a[4];
    #pragma unroll
    for (int qq = 0; qq < 4; ++qq) a[qq] = make_float4(0.f, 0.f, 0.f, 0.f);
    for (int i = 0; i < 128; ++i) {
        float h1 = fmaf(x2, sW1[2][i], fmaf(x1, sW1[1][i], fmaf(x0, sW1[0][i], zp[i])));
        h1 = fmaxf(h1, 0.0f);
        #pragma unroll
        for (int qq = 0; qq < 4; ++qq) {
            float4 wv = sW2[i][w*4 + qq];
            a[qq].x = fmaf(h1, wv.x, a[qq].x);
            a[qq].y = fmaf(h1, wv.y, a[qq].y);
            a[qq].z = fmaf(h1, wv.z, a[qq].z);
            a[qq].w = fmaf(h1, wv.w, a[qq].w);
        }
    }
    float p0 = 0.f, p1 = 0.f, p2 = 0.f;
    #pragma unroll
    for (int qq = 0; qq < 4; ++qq) {
        float av[4] = {a[qq].x, a[qq].y, a[qq].z, a[qq].w};
        #pragma unroll
        for (int cc = 0; cc < 4; ++cc) {
            int j = w*16 + qq*4 + cc;
            float h2 = fmaxf(av[cc] + sB2[j], 0.0f);
            p0 = fmaf(h2, sW3[j][0], p0);
            p1 = fmaf(h2, sW3[j][1], p1);
            p2 = fmaf(h2, sW3[j][2], p2);
        }
    }
    sE[0][w][lane] = p0; sE[1][w][lane] = p1; sE[2][w][lane] = p2;
    __syncthreads();
    if (w == 0) {
        float ee0 = ((sE[0][0][lane] + sE[0][1][lane]) + sE[0][2][lane]) + sE[0][3][lane] + sB3[0];
        float ee1 = ((sE[1][0][lane] + sE[1][1][lane]) + sE[1][2][lane]) + sE[1][3][lane] + sB3[1];
        float ee2 = ((sE[2][0][lane] + sE[2][1][lane]) + sE[2][2][lane]) + sE[2][3][lane] + sB3[2];
        const float* gsp = ws + OFF_GS + (size_t)g*4;
        float d0 = ee0 - gsp[0], d1 = ee1 - gsp[1], d2 = ee2 - gsp[2];
        float t = ((d0*d0 + d1*d1) + d2*d2) * 100.0f;
        for (int off = 32; off > 0; off >>= 1) t += __shfl_down(t, off);
        if (lane == 0) atomicAdd(ws + OFF_AC, t);
    }
}

// ---------------- Stage 6: finalize --------------------------------------------
__global__ void k_fin(const float* __restrict__ ws, float* __restrict__ out) {
    if (threadIdx.x == 0 && blockIdx.x == 0)
        out[0] = ws[OFF_AC] * (1.0f / 32768.0f);
}

extern "C" void kernel_launch(void* const* d_in, const int* in_sizes, int n_in,
                              void* d_out, int out_size, void* d_ws, size_t ws_size,
                              hipStream_t stream) {
    const float* noisy = (const float*)d_in[0];
    const float* clean = (const float*)d_in[1];
    const int*   sidx  = (const int*)  d_in[2];
    const float* Wf1 = (const float*)d_in[3];
    const float* bf1 = (const float*)d_in[4];
    const float* Wf2 = (const float*)d_in[5];
    const float* bf2 = (const float*)d_in[6];
    const float* Ws1 = (const float*)d_in[7];
    const float* bs1 = (const float*)d_in[8];
    const float* Ws2 = (const float*)d_in[9];
    const float* bs2 = (const float*)d_in[10];
    const float* Ws3 = (const float*)d_in[11];
    const float* bs3 = (const float*)d_in[12];
    float* ws  = (float*)d_ws;
    float* out = (float*)d_out;

    k_pack<<<(BB*NN + BB*MM + 255)/256, 256, 0, stream>>>(noisy, clean, ws);
    k_feat<<<(BB*PP*64)/256, 256, 0, stream>>>(sidx, Wf1, bf1, Wf2, bf2, Ws1, bs1, ws);
    k_knn1<<<(BB*PP)/4, 256, 0, stream>>>(sidx, ws);
    k_knn2<<<(BB*PP*KS)/QPB, 256, 0, stream>>>(ws);
    k_mlp<<<(BB*PP*KS)/64, 256, 0, stream>>>(Ws1, Ws2, bs2, Ws3, bs3, ws);
    k_fin<<<1, 64, 0, stream>>>(ws, out);
}

// Round 7
// 230.146 us; speedup vs baseline: 1.3687x; 1.3687x over previous
//
#include <hip/hip_runtime.h>

#define BB 4
#define NN 10000
#define MM 10000
#define PP 128
#define KS 32
#define KSC 4
#define ZZ 128

// workspace layout in floats (all offsets 16B-aligned)
#define OFF_PN 0                       // packed noisy  [B][N][4] (x,y,z,|p|^2)
#define OFF_PC (OFF_PN + BB*NN*4)      // packed clean  [B][M][4] (x,y,z,-|c|^2/2)
#define OFF_FO (OFF_PC + BB*MM*4)      // f_origin      [B][P][4]
#define OFF_ZP (OFF_FO + BB*PP*4)      // zpart         [B][P][128]
#define OFF_FP (OFF_ZP + BB*PP*ZZ)     // f points      [B][P][K][4]
#define OFF_GS (OFF_FP + BB*PP*KS*4)   // ground score  [B][P][K][4]
#define OFF_AC (OFF_GS + BB*PP*KS*4)   // loss accumulator [1]

#define FINF 1e30f

// ---------------- Stage 1: pack points; zero accumulator -----------------------
__global__ void k_pack(const float* __restrict__ noisy, const float* __restrict__ clean,
                       float* __restrict__ ws) {
    int t = blockIdx.x * blockDim.x + threadIdx.x;
    if (t == 0) ws[OFF_AC] = 0.0f;
    const int total = BB*NN + BB*MM;
    if (t >= total) return;
    if (t < BB*NN) {
        float x = noisy[t*3+0], y = noisy[t*3+1], z = noisy[t*3+2];
        float w = (x*x + y*y) + z*z;
        ((float4*)(ws + OFF_PN))[t] = make_float4(x, y, z, w);
    } else {
        int u = t - BB*NN;
        float x = clean[u*3+0], y = clean[u*3+1], z = clean[u*3+2];
        float w = -0.5f * ((x*x + y*y) + z*z);
        ((float4*)(ws + OFF_PC))[u] = make_float4(x, y, z, w);
    }
}

// ---------------- Stage 2: per sampled point: f_origin, feat MLP, zpart --------
__global__ void k_feat(const int* __restrict__ sidx,
                       const float* __restrict__ Wf1, const float* __restrict__ bf1,
                       const float* __restrict__ Wf2, const float* __restrict__ bf2,
                       const float* __restrict__ Ws1, const float* __restrict__ bs1,
                       float* __restrict__ ws) {
    int wave = (blockIdx.x * blockDim.x + threadIdx.x) >> 6;
    int lane = threadIdx.x & 63;
    if (wave >= BB*PP) return;
    int b = wave / PP, p = wave % PP;
    int si = sidx[p];
    float4 q = ((const float4*)(ws + OFF_PN))[b*NN + si];
    if (lane == 0) ((float4*)(ws + OFF_FO))[wave] = q;
    float h = bf1[lane];
    h = fmaf(q.x, Wf1[0*64 + lane], h);
    h = fmaf(q.y, Wf1[1*64 + lane], h);
    h = fmaf(q.z, Wf1[2*64 + lane], h);
    h = fmaxf(h, 0.0f);
    float fa = bf2[lane], fb = bf2[64 + lane];
    for (int i = 0; i < 64; ++i) {
        float hi = __shfl(h, i);
        fa = fmaf(hi, Wf2[i*ZZ + lane],      fa);
        fb = fmaf(hi, Wf2[i*ZZ + 64 + lane], fb);
    }
    float za = bs1[lane], zb = bs1[64 + lane];
    for (int i = 0; i < 64; ++i) {
        float va = __shfl(fa, i);
        float vb = __shfl(fb, i);
        za = fmaf(va, Ws1[(3 + i)*128 + lane],       za);
        zb = fmaf(va, Ws1[(3 + i)*128 + 64 + lane],  zb);
        za = fmaf(vb, Ws1[(67 + i)*128 + lane],      za);
        zb = fmaf(vb, Ws1[(67 + i)*128 + 64 + lane], zb);
    }
    ws[OFF_ZP + wave*ZZ + lane]      = za;
    ws[OFF_ZP + wave*ZZ + 64 + lane] = zb;
}

// ---------------- Stage 3: knn1 — block-per-query, 2-pass tau-gated ------------
// 512 blocks x 256 thr. Pass 1: per-thread branchless top-2 over stride-256
// stream; per-wave tau_w = 32nd of pooled 128 (subset k-th >= full k-th);
// tau = min over 4 waves (still >= true d32 -> gate keeps all true top-32).
// Pass 2: gated collect to LDS; exact (d,idx)-lex rank-select.
#define CAP1 512
__global__ __launch_bounds__(256) void k_knn1(const int* __restrict__ sidx, float* __restrict__ ws) {
    __shared__ float cd[CAP1];
    __shared__ int   ci[CAP1];
    __shared__ float wtau[4];
    __shared__ int   cnt;
    int blk = blockIdx.x;               // global query id in [0,512)
    int b = blk >> 7, p = blk & 127;
    int tid = threadIdx.x;
    int w = tid >> 6, lane = tid & 63;
    const float4* pts = ((const float4*)(ws + OFF_PN)) + b*NN;
    float4 q = pts[sidx[p]];
    if (tid == 0) cnt = 0;
    float t0 = FINF, t1 = FINF;
    for (int j = tid; j < NN; j += 256) {
        float4 r = pts[j];
        float dot = fmaf(q.z, r.z, fmaf(q.y, r.y, q.x*r.x));
        float d = fmaf(dot, -2.0f, q.w + r.w);
        t1 = fminf(t1, fmaxf(t0, d));
        t0 = fminf(t0, d);
    }
    float m = 0.0f;
    for (int r = 0; r < KS; ++r) {
        m = t0;
        m = fminf(m, __shfl_xor(m, 1));
        m = fminf(m, __shfl_xor(m, 2));
        m = fminf(m, __shfl_xor(m, 4));
        m = fminf(m, __shfl_xor(m, 8));
        m = fminf(m, __shfl_xor(m, 16));
        m = fminf(m, __shfl_xor(m, 32));
        if (t0 == m) { t0 = t1; t1 = FINF; }
    }
    if (lane == 0) wtau[w] = m;
    __syncthreads();
    float tau = fminf(fminf(wtau[0], wtau[1]), fminf(wtau[2], wtau[3]));
    for (int j = tid; j < NN; j += 256) {
        float4 r = pts[j];
        float dot = fmaf(q.z, r.z, fmaf(q.y, r.y, q.x*r.x));
        float d = fmaf(dot, -2.0f, q.w + r.w);
        if (d <= tau) {
            int pos = atomicAdd(&cnt, 1);
            if (pos < CAP1) { cd[pos] = d; ci[pos] = j; }
        }
    }
    __syncthreads();
    int C = cnt; if (C > CAP1) C = CAP1;
    for (int i = tid; i < C; i += 256) {
        float di = cd[i]; int ii = ci[i];
        int rank = 0;
        for (int j2 = 0; j2 < C; ++j2) {
            float dj = cd[j2]; int ij = ci[j2];
            rank += ((dj < di) || (dj == di && ij < ii)) ? 1 : 0;
        }
        if (rank < KS) ((float4*)(ws + OFF_FP))[blk*KS + rank] = pts[ii];
    }
}

// ---------------- Stage 4: knn2 — Q=4 flat named-scalar, static-tau gated ------
// 512 blocks x 256 thr, 32 queries/block. Wave covers ALL 32 q (8 subs x 8
// qgroups x Q=4); 4 waves split the stream (500-pt slices of 2000-pt chunks).
// One ds_read_b128 serves 8 pts x 32 q = 256 pairs. e = dot - |c|^2/2.
// Phase A: branchless top-2/thread over chunk 0 -> exact pool-4th = tau (static;
// subset-4th <= global-4th => gate e>=tau keeps all true top-4). Phase B: gated
// sorted-insert on named scalars only (no arrays -> no scratch).
#define CHK2 2000
#define QPB 32

#define KDECL(c) \
    float fxv##c, fyv##c, fzv##c, tauv##c; \
    float te0##c=-FINF, te1##c=-FINF, te2##c=-FINF, te3##c=-FINF; \
    int   ti0##c=-1,   ti1##c=-1,   ti2##c=-1,   ti3##c=-1; \
    float ta0##c=-FINF, ta1##c=-FINF;

#define KLOAD(c) { float4 f4_ = ((const float4*)(ws + OFF_FP))[qbase + qg*4 + c]; \
    fxv##c = f4_.x; fyv##c = f4_.y; fzv##c = f4_.z; }

#define AUPD(c, R) { float e_ = fmaf(fzv##c,(R).z,fmaf(fyv##c,(R).y,fmaf(fxv##c,(R).x,(R).w))); \
    ta1##c = fmaxf(ta1##c, fminf(ta0##c, e_)); ta0##c = fmaxf(ta0##c, e_); }

#define AMRG(c) { \
    float h0_ = ta0##c, h1_ = ta1##c; \
    _Pragma("unroll") \
    for (int r_ = 0; r_ < 4; ++r_) { \
        float m_ = h0_; \
        m_ = fmaxf(m_, __shfl_xor(m_, 1)); \
        m_ = fmaxf(m_, __shfl_xor(m_, 2)); \
        m_ = fmaxf(m_, __shfl_xor(m_, 4)); \
        if (h0_ == m_) { h0_ = h1_; h1_ = -FINF; } \
        if (sub == r_) sWA[qg*4 + c][w*4 + r_] = m_; \
    } }

#define EVC(c, R) float ev##c = fmaf(fzv##c,(R).z,fmaf(fyv##c,(R).y,fmaf(fxv##c,(R).x,(R).w)));

#define INSC(c, JV) { \
    if (ev##c >= tauv##c && ev##c > te3##c) { \
        if (ev##c > te1##c) { \
            te3##c = te2##c; ti3##c = ti2##c; te2##c = te1##c; ti2##c = ti1##c; \
            if (ev##c > te0##c) { te1##c = te0##c; ti1##c = ti0##c; te0##c = ev##c; ti0##c = (JV); } \
            else                { te1##c = ev##c; ti1##c = (JV); } \
        } else if (ev##c > te2##c) { te3##c = te2##c; ti3##c = ti2##c; te2##c = ev##c; ti2##c = (JV); } \
        else                       { te3##c = ev##c; ti3##c = (JV); } \
    } }

#define BSCAN(BUF, BASE) \
    for (int t_ = 0; t_ < 63; ++t_) { \
        if (t_ < 62 || sub < 4) { \
            int loc_ = sbase + t_*8 + sub; \
            float4 r_ = sp[BUF][loc_]; \
            EVC(0, r_) EVC(1, r_) EVC(2, r_) EVC(3, r_) \
            float mx_ = fmaxf(fmaxf(ev0, ev1), fmaxf(ev2, ev3)); \
            if (mx_ >= cmin) { \
                int gj_ = (BASE) + loc_; \
                INSC(0, gj_) INSC(1, gj_) INSC(2, gj_) INSC(3, gj_) \
            } \
        } }

#define BMRG(c) { \
    _Pragma("unroll") \
    for (int r_ = 0; r_ < 4; ++r_) { \
        float bk_ = te0##c; int bi_ = ti0##c; int bl_ = lane; \
        _Pragma("unroll") \
        for (int off_ = 1; off_ < 8; off_ <<= 1) { \
            float ok_ = __shfl_xor(bk_, off_); \
            int   oi_ = __shfl_xor(bi_, off_); \
            int   ol_ = __shfl_xor(bl_, off_); \
            if (ok_ > bk_ || (ok_ == bk_ && oi_ < bi_)) { bk_ = ok_; bi_ = oi_; bl_ = ol_; } \
        } \
        if (sub == r_) { sME[qg*4 + c][w*4 + r_] = bk_; sMI[qg*4 + c][w*4 + r_] = bi_; } \
        if (lane == bl_) { te0##c = te1##c; ti0##c = ti1##c; te1##c = te2##c; ti1##c = ti2##c; \
                           te2##c = te3##c; ti2##c = ti3##c; te3##c = -FINF; ti3##c = -1; } \
    } }

#define STAGE(BUF, CHUNK) \
    for (int u_ = tid; u_ < CHK2; u_ += 256) sp[BUF][u_] = pts[(CHUNK)*CHK2 + u_];

__global__ __launch_bounds__(256) void k_knn2(float* __restrict__ ws) {
    __shared__ float4 sp[2][CHK2];
    __shared__ float  sWA[QPB][16];
    __shared__ float  sME[QPB][16];
    __shared__ int    sMI[QPB][16];
    __shared__ float  sTau[QPB];
    int tid  = threadIdx.x;
    int w    = tid >> 6;
    int lane = tid & 63;
    int sub  = lane & 7;
    int qg   = lane >> 3;
    int qbase = blockIdx.x * QPB;
    int b = qbase >> 12;
    int sbase = w * 500;
    const float4* pts = ((const float4*)(ws + OFF_PC)) + b*MM;

    KDECL(0) KDECL(1) KDECL(2) KDECL(3)
    KLOAD(0) KLOAD(1) KLOAD(2) KLOAD(3)

    STAGE(0, 0)
    __syncthreads();
    STAGE(1, 1)                          // loads in flight under phase A

    // ---- phase A: branchless top-2 sample over chunk 0 (stream-split) ----
    for (int t_ = 0; t_ < 63; ++t_) {
        if (t_ < 62 || sub < 4) {
            float4 r_ = sp[0][sbase + t_*8 + sub];
            AUPD(0, r_) AUPD(1, r_) AUPD(2, r_) AUPD(3, r_)
        }
    }
    AMRG(0) AMRG(1) AMRG(2) AMRG(3)
    __syncthreads();                     // sWA ready AND chunk 1 staged
    if (tid < QPB) {
        float b0=-FINF, b1=-FINF, b2=-FINF, b3=-FINF;
        #pragma unroll
        for (int u = 0; u < 16; ++u) {
            float v = sWA[tid][u];
            b3 = fmaxf(b3, fminf(b2, v));
            b2 = fmaxf(b2, fminf(b1, v));
            b1 = fmaxf(b1, fminf(b0, v));
            b0 = fmaxf(b0, v);
        }
        sTau[tid] = b3;                  // exact pool-4th (ties only loosen)
    }
    __syncthreads();
    tauv0 = sTau[qg*4 + 0]; tauv1 = sTau[qg*4 + 1];
    tauv2 = sTau[qg*4 + 2]; tauv3 = sTau[qg*4 + 3];
    float cmin = fminf(fminf(tauv0, tauv1), fminf(tauv2, tauv3));

    // ---- phase B: gated exact scan, double-buffered ----
    BSCAN(0, 0)
    __syncthreads();
    STAGE(0, 2) BSCAN(1, CHK2)
    __syncthreads();
    STAGE(1, 3) BSCAN(0, 2*CHK2)
    __syncthreads();
    STAGE(0, 4) BSCAN(1, 3*CHK2)
    __syncthreads();
    BSCAN(0, 4*CHK2)

    // ---- per-wave lex top-4 -> LDS; cross-wave exact merge ----
    BMRG(0) BMRG(1) BMRG(2) BMRG(3)
    __syncthreads();
    if (tid < QPB) {
        int q = qbase + tid;
        float4 f4 = ((const float4*)(ws + OFF_FP))[q];
        float b0=-FINF, b1=-FINF, b2=-FINF, b3=-FINF;
        int   j0=-1,   j1=-1,   j2=-1,   j3=-1;
        #pragma unroll
        for (int u = 0; u < 16; ++u) {
            float e = sME[tid][u]; int ii = sMI[tid][u];
            bool l3 = (e > b3) || (e == b3 && ii < j3);
            if (l3) {
                bool l2 = (e > b2) || (e == b2 && ii < j2);
                if (l2) {
                    b3 = b2; j3 = j2;
                    bool l1 = (e > b1) || (e == b1 && ii < j1);
                    if (l1) {
                        b2 = b1; j2 = j1;
                        bool l0 = (e > b0) || (e == b0 && ii < j0);
                        if (l0) { b1 = b0; j1 = j0; b0 = e; j0 = ii; }
                        else    { b1 = e; j1 = ii; }
                    } else { b2 = e; j2 = ii; }
                } else { b3 = e; j3 = ii; }
            }
        }
        float4 n0 = pts[j0], n1 = pts[j1], n2 = pts[j2], n3 = pts[j3];
        float gx = 0.f, gy = 0.f, gz = 0.f;
        gx += n0.x - f4.x; gy += n0.y - f4.y; gz += n0.z - f4.z;
        gx += n1.x - f4.x; gy += n1.y - f4.y; gz += n1.z - f4.z;
        gx += n2.x - f4.x; gy += n2.y - f4.y; gz += n2.z - f4.z;
        gx += n3.x - f4.x; gy += n3.y - f4.y; gz += n3.z - f4.z;
        float* gsp = ws + OFF_GS + (size_t)q*4;
        gsp[0] = gx*0.25f; gsp[1] = gy*0.25f; gsp[2] = gz*0.25f;
    }
}

// ---------------- Stage 5: score MLP + loss — 4-wave j-split, packed g4 --------
__global__ __launch_bounds__(256) void k_mlp(const float* __restrict__ Ws1,
                                             const float* __restrict__ Ws2, const float* __restrict__ bs2,
                                             const float* __restrict__ Ws3, const float* __restrict__ bs3,
                                             float* __restrict__ ws) {
    __shared__ float4 sG[2][128];        // (zp_i, W1[0][i], W1[1][i], W1[2][i])
    __shared__ float4 sW2[128][16];
    __shared__ float  sB2[64];
    __shared__ float  sW3[64][3];
    __shared__ float  sB3[3];
    __shared__ float  sE[3][4][64];
    int tid = threadIdx.x;
    int w = tid >> 6, lane = tid & 63;
    for (int u = tid; u < 2048; u += 256) ((float4*)sW2)[u] = ((const float4*)Ws2)[u];
    if (tid < 64) sB2[tid] = bs2[tid];
    if (tid < 192) ((float*)sW3)[tid] = Ws3[tid];
    if (tid < 3) sB3[tid] = bs3[tid];
    {
        int grp = tid >> 7, i = tid & 127;
        sG[grp][i] = make_float4(ws[OFF_ZP + (blockIdx.x*2 + grp)*ZZ + i],
                                 Ws1[i], Ws1[128 + i], Ws1[256 + i]);
    }
    __syncthreads();

    int g = blockIdx.x*64 + lane;
    float4 f4 = ((const float4*)(ws + OFF_FP))[g];
    float4 fo = ((const float4*)(ws + OFF_FO))[g >> 5];
    float x0 = f4.x - fo.x, x1 = f4.y - fo.y, x2 = f4.z - fo.z;
    int grp = lane >> 5;

    float4 a[4];
    #pragma unroll
    for (int qq = 0; qq < 4; ++qq) a[qq] = make_float4(0.f, 0.f, 0.f, 0.f);
    for (int i = 0; i < 128; ++i) {
        float4 gv = sG[grp][i];
        float h1 = fmaf(x2, gv.w, fmaf(x1, gv.z, fmaf(x0, gv.y, gv.x)));
        h1 = fmaxf(h1, 0.0f);
        #pragma unroll
        for (int qq = 0; qq < 4; ++qq) {
            float4 wv = sW2[i][w*4 + qq];
            a[qq].x = fmaf(h1, wv.x, a[qq].x);
            a[qq].y = fmaf(h1, wv.y, a[qq].y);
            a[qq].z = fmaf(h1, wv.z, a[qq].z);
            a[qq].w = fmaf(h1, wv.w, a[qq].w);
        }
    }
    float p0 = 0.f, p1 = 0.f, p2 = 0.f;
    #pragma unroll
    for (int qq = 0; qq < 4; ++qq) {
        float av[4] = {a[qq].x, a[qq].y, a[qq].z, a[qq].w};
        #pragma unroll
        for (int cc = 0; cc < 4; ++cc) {
            int j = w*16 + qq*4 + cc;
            float h2 = fmaxf(av[cc] + sB2[j], 0.0f);
            p0 = fmaf(h2, sW3[j][0], p0);
            p1 = fmaf(h2, sW3[j][1], p1);
            p2 = fmaf(h2, sW3[j][2], p2);
        }
    }
    sE[0][w][lane] = p0; sE[1][w][lane] = p1; sE[2][w][lane] = p2;
    __syncthreads();
    if (w == 0) {
        float ee0 = ((sE[0][0][lane] + sE[0][1][lane]) + sE[0][2][lane]) + sE[0][3][lane] + sB3[0];
        float ee1 = ((sE[1][0][lane] + sE[1][1][lane]) + sE[1][2][lane]) + sE[1][3][lane] + sB3[1];
        float ee2 = ((sE[2][0][lane] + sE[2][1][lane]) + sE[2][2][lane]) + sE[2][3][lane] + sB3[2];
        const float* gsp = ws + OFF_GS + (size_t)g*4;
        float d0 = ee0 - gsp[0], d1 = ee1 - gsp[1], d2 = ee2 - gsp[2];
        float t = ((d0*d0 + d1*d1) + d2*d2) * 100.0f;
        for (int off = 32; off > 0; off >>= 1) t += __shfl_down(t, off);
        if (lane == 0) atomicAdd(ws + OFF_AC, t);
    }
}

// ---------------- Stage 6: finalize --------------------------------------------
__global__ void k_fin(const float* __restrict__ ws, float* __restrict__ out) {
    if (threadIdx.x == 0 && blockIdx.x == 0)
        out[0] = ws[OFF_AC] * (1.0f / 32768.0f);
}

extern "C" void kernel_launch(void* const* d_in, const int* in_sizes, int n_in,
                              void* d_out, int out_size, void* d_ws, size_t ws_size,
                              hipStream_t stream) {
    const float* noisy = (const float*)d_in[0];
    const float* clean = (const float*)d_in[1];
    const int*   sidx  = (const int*)  d_in[2];
    const float* Wf1 = (const float*)d_in[3];
    const float* bf1 = (const float*)d_in[4];
    const float* Wf2 = (const float*)d_in[5];
    const float* bf2 = (const float*)d_in[6];
    const float* Ws1 = (const float*)d_in[7];
    const float* bs1 = (const float*)d_in[8];
    const float* Ws2 = (const float*)d_in[9];
    const float* bs2 = (const float*)d_in[10];
    const float* Ws3 = (const float*)d_in[11];
    const float* bs3 = (const float*)d_in[12];
    float* ws  = (float*)d_ws;
    float* out = (float*)d_out;

    k_pack<<<(BB*NN + BB*MM + 255)/256, 256, 0, stream>>>(noisy, clean, ws);
    k_feat<<<(BB*PP*64)/256, 256, 0, stream>>>(sidx, Wf1, bf1, Wf2, bf2, Ws1, bs1, ws);
    k_knn1<<<BB*PP, 256, 0, stream>>>(sidx, ws);
    k_knn2<<<(BB*PP*KS)/QPB, 256, 0, stream>>>(ws);
    k_mlp<<<(BB*PP*KS)/64, 256, 0, stream>>>(Ws1, Ws2, bs2, Ws3, bs3, ws);
    k_fin<<<1, 64, 0, stream>>>(ws, out);
}

// Round 8
// 220.857 us; speedup vs baseline: 1.4263x; 1.0421x over previous
//
#include <hip/hip_runtime.h>

#define BB 4
#define NN 10000
#define MM 10000
#define PP 128
#define KS 32
#define KSC 4
#define ZZ 128

// workspace layout in floats (all offsets 16B-aligned)
#define OFF_PN 0                       // packed noisy  [B][N][4] (x,y,z,|p|^2)
#define OFF_PC (OFF_PN + BB*NN*4)      // packed clean  [B][M][4] (x,y,z,-|c|^2/2)
#define OFF_FO (OFF_PC + BB*MM*4)      // f_origin      [B][P][4]
#define OFF_ZP (OFF_FO + BB*PP*4)      // zpart         [B][P][128]
#define OFF_FP (OFF_ZP + BB*PP*ZZ)     // f points      [B][P][K][4]
#define OFF_GS (OFF_FP + BB*PP*KS*4)   // ground score  [B][P][K][4]
#define OFF_AC (OFF_GS + BB*PP*KS*4)   // loss accumulator [1]

#define FINF 1e30f

// ---------------- Stage 1: pack points; zero accumulator -----------------------
__global__ void k_pack(const float* __restrict__ noisy, const float* __restrict__ clean,
                       float* __restrict__ ws) {
    int t = blockIdx.x * blockDim.x + threadIdx.x;
    if (t == 0) ws[OFF_AC] = 0.0f;
    const int total = BB*NN + BB*MM;
    if (t >= total) return;
    if (t < BB*NN) {
        float x = noisy[t*3+0], y = noisy[t*3+1], z = noisy[t*3+2];
        float w = (x*x + y*y) + z*z;
        ((float4*)(ws + OFF_PN))[t] = make_float4(x, y, z, w);
    } else {
        int u = t - BB*NN;
        float x = clean[u*3+0], y = clean[u*3+1], z = clean[u*3+2];
        float w = -0.5f * ((x*x + y*y) + z*z);
        ((float4*)(ws + OFF_PC))[u] = make_float4(x, y, z, w);
    }
}

// ---------------- Stage 2: per sampled point: f_origin, feat MLP, zpart --------
__global__ void k_feat(const int* __restrict__ sidx,
                       const float* __restrict__ Wf1, const float* __restrict__ bf1,
                       const float* __restrict__ Wf2, const float* __restrict__ bf2,
                       const float* __restrict__ Ws1, const float* __restrict__ bs1,
                       float* __restrict__ ws) {
    int wave = (blockIdx.x * blockDim.x + threadIdx.x) >> 6;
    int lane = threadIdx.x & 63;
    if (wave >= BB*PP) return;
    int b = wave / PP, p = wave % PP;
    int si = sidx[p];
    float4 q = ((const float4*)(ws + OFF_PN))[b*NN + si];
    if (lane == 0) ((float4*)(ws + OFF_FO))[wave] = q;
    float h = bf1[lane];
    h = fmaf(q.x, Wf1[0*64 + lane], h);
    h = fmaf(q.y, Wf1[1*64 + lane], h);
    h = fmaf(q.z, Wf1[2*64 + lane], h);
    h = fmaxf(h, 0.0f);
    float fa = bf2[lane], fb = bf2[64 + lane];
    for (int i = 0; i < 64; ++i) {
        float hi = __shfl(h, i);
        fa = fmaf(hi, Wf2[i*ZZ + lane],      fa);
        fb = fmaf(hi, Wf2[i*ZZ + 64 + lane], fb);
    }
    float za = bs1[lane], zb = bs1[64 + lane];
    for (int i = 0; i < 64; ++i) {
        float va = __shfl(fa, i);
        float vb = __shfl(fb, i);
        za = fmaf(va, Ws1[(3 + i)*128 + lane],       za);
        zb = fmaf(va, Ws1[(3 + i)*128 + 64 + lane],  zb);
        za = fmaf(vb, Ws1[(67 + i)*128 + lane],      za);
        zb = fmaf(vb, Ws1[(67 + i)*128 + 64 + lane], zb);
    }
    ws[OFF_ZP + wave*ZZ + lane]      = za;
    ws[OFF_ZP + wave*ZZ + 64 + lane] = zb;
}

// ---------------- Stage 3: knn1 — block-per-query, 2-pass tau-gated ------------
#define CAP1 512
__global__ __launch_bounds__(256) void k_knn1(const int* __restrict__ sidx, float* __restrict__ ws) {
    __shared__ float cd[CAP1];
    __shared__ int   ci[CAP1];
    __shared__ float wtau[4];
    __shared__ int   cnt;
    int blk = blockIdx.x;               // global query id in [0,512)
    int b = blk >> 7, p = blk & 127;
    int tid = threadIdx.x;
    int w = tid >> 6, lane = tid & 63;
    const float4* pts = ((const float4*)(ws + OFF_PN)) + b*NN;
    float4 q = pts[sidx[p]];
    if (tid == 0) cnt = 0;
    float t0 = FINF, t1 = FINF;
    for (int j = tid; j < NN; j += 256) {
        float4 r = pts[j];
        float dot = fmaf(q.z, r.z, fmaf(q.y, r.y, q.x*r.x));
        float d = fmaf(dot, -2.0f, q.w + r.w);
        t1 = fminf(t1, fmaxf(t0, d));
        t0 = fminf(t0, d);
    }
    float m = 0.0f;
    for (int r = 0; r < KS; ++r) {
        m = t0;
        m = fminf(m, __shfl_xor(m, 1));
        m = fminf(m, __shfl_xor(m, 2));
        m = fminf(m, __shfl_xor(m, 4));
        m = fminf(m, __shfl_xor(m, 8));
        m = fminf(m, __shfl_xor(m, 16));
        m = fminf(m, __shfl_xor(m, 32));
        if (t0 == m) { t0 = t1; t1 = FINF; }
    }
    if (lane == 0) wtau[w] = m;
    __syncthreads();
    float tau = fminf(fminf(wtau[0], wtau[1]), fminf(wtau[2], wtau[3]));
    for (int j = tid; j < NN; j += 256) {
        float4 r = pts[j];
        float dot = fmaf(q.z, r.z, fmaf(q.y, r.y, q.x*r.x));
        float d = fmaf(dot, -2.0f, q.w + r.w);
        if (d <= tau) {
            int pos = atomicAdd(&cnt, 1);
            if (pos < CAP1) { cd[pos] = d; ci[pos] = j; }
        }
    }
    __syncthreads();
    int C = cnt; if (C > CAP1) C = CAP1;
    for (int i = tid; i < C; i += 256) {
        float di = cd[i]; int ii = ci[i];
        int rank = 0;
        for (int j2 = 0; j2 < C; ++j2) {
            float dj = cd[j2]; int ij = ci[j2];
            rank += ((dj < di) || (dj == di && ij < ii)) ? 1 : 0;
        }
        if (rank < KS) ((float4*)(ws + OFF_FP))[blk*KS + rank] = pts[ii];
    }
}

// ---------------- Stage 4: knn2 — append-list, static-tau gated ----------------
// 512 blocks x 512 thr (8 waves), 32 queries/block. Lane = 8 subs x 8 qgroups,
// Q=4 queries/thread (named scalars); 8 waves split each 1000-pt chunk (125
// each). One ds_read_b128 serves 8 pts x 32 q = 256 pair-evals.
// e = dot - |c|^2/2 (max-e == min-d). Phase A: branchless top-2/thread over
// chunks 0-1 -> octet shfl top-4 -> per-query 4th of 32 = pool-4th = tau
// (subset => tau <= true 4th => gate e>=tau keeps all true top-4).
// Phase B: gated APPEND to per-query LDS list (atomic; ~10-inst body).
// Phase C: exact (e desc, idx asc)-lex rank-select == jax stable top_k;
// GS accumulated in rank order (bit-identical to prior rounds).
#define CHK2 1000
#define NCH2 10
#define QPB 32
#define CAP2 128

#define K2Q(c) float fxv##c, fyv##c, fzv##c, tauv##c; \
    float ta0##c = -FINF, ta1##c = -FINF;

#define K2LOAD(c) { float4 f4_ = ((const float4*)(ws + OFF_FP))[qbase + qg*4 + c]; \
    fxv##c = f4_.x; fyv##c = f4_.y; fzv##c = f4_.z; }

#define AUPD(c, R) { float e_ = fmaf(fzv##c,(R).z,fmaf(fyv##c,(R).y,fmaf(fxv##c,(R).x,(R).w))); \
    ta1##c = fmaxf(ta1##c, fminf(ta0##c, e_)); ta0##c = fmaxf(ta0##c, e_); }

#define ASCAN(BUF) \
    for (int t_ = 0; t_ < 16; ++t_) { \
        if (t_ < 15 || sub < 5) { \
            float4 r_ = sp[BUF][sbase + t_*8 + sub]; \
            AUPD(0, r_) AUPD(1, r_) AUPD(2, r_) AUPD(3, r_) \
        } }

#define AMRG(c) { \
    float h0_ = ta0##c, h1_ = ta1##c; \
    _Pragma("unroll") \
    for (int r_ = 0; r_ < 4; ++r_) { \
        float m_ = h0_; \
        m_ = fmaxf(m_, __shfl_xor(m_, 1)); \
        m_ = fmaxf(m_, __shfl_xor(m_, 2)); \
        m_ = fmaxf(m_, __shfl_xor(m_, 4)); \
        if (h0_ == m_) { h0_ = h1_; h1_ = -FINF; } \
        if (sub == r_) sWA[qg*4 + c][w*4 + r_] = m_; \
    } }

#define EVC(c, R) float ev##c = fmaf(fzv##c,(R).z,fmaf(fyv##c,(R).y,fmaf(fxv##c,(R).x,(R).w)));

#define APP(c) if (ev##c >= tauv##c) { \
    int pos_ = atomicAdd(&sCnt[qg*4 + c], 1); \
    if (pos_ < CAP2) { sCE[qg*4 + c][pos_] = ev##c; sCI[qg*4 + c][pos_] = gj_; } }

#define BSCAN(BUF, BASE) \
    for (int t_ = 0; t_ < 16; ++t_) { \
        if (t_ < 15 || sub < 5) { \
            int loc_ = sbase + t_*8 + sub; \
            float4 r_ = sp[BUF][loc_]; \
            EVC(0, r_) EVC(1, r_) EVC(2, r_) EVC(3, r_) \
            float mx_ = fmaxf(fmaxf(ev0, ev1), fmaxf(ev2, ev3)); \
            if (mx_ >= cmin) { \
                int gj_ = (BASE) + loc_; \
                APP(0) APP(1) APP(2) APP(3) \
            } \
        } }

#define STAGE(BUF, CHUNK) \
    for (int u_ = tid; u_ < CHK2; u_ += 512) sp[BUF][u_] = pts[(CHUNK)*CHK2 + u_];

__global__ __launch_bounds__(512) void k_knn2(float* __restrict__ ws) {
    __shared__ float4 sp[2][CHK2];
    __shared__ float  sWA[QPB][33];
    __shared__ float  sCE[QPB][CAP2 + 1];
    __shared__ int    sCI[QPB][CAP2 + 1];
    __shared__ float  sTau[QPB];
    __shared__ int    sCnt[QPB];
    __shared__ int    sTop[QPB][4];
    int tid  = threadIdx.x;
    int w    = tid >> 6;                // 0..7
    int lane = tid & 63;
    int sub  = lane & 7;
    int qg   = lane >> 3;
    int qbase = blockIdx.x * QPB;
    int b = qbase >> 12;
    int sbase = w * 125;
    const float4* pts = ((const float4*)(ws + OFF_PC)) + b*MM;

    K2Q(0) K2Q(1) K2Q(2) K2Q(3)
    K2LOAD(0) K2LOAD(1) K2LOAD(2) K2LOAD(3)
    if (tid < QPB) sCnt[tid] = 0;

    STAGE(0, 0)
    __syncthreads();
    STAGE(1, 1)                          // in flight under phase A on chunk 0

    // ---- phase A: sample = chunks 0+1 ----
    ASCAN(0)
    __syncthreads();                     // chunk 1 staged
    ASCAN(1)
    AMRG(0) AMRG(1) AMRG(2) AMRG(3)
    __syncthreads();
    if (tid < QPB) {
        float b0 = -FINF, b1 = -FINF, b2 = -FINF, b3 = -FINF;
        #pragma unroll
        for (int u = 0; u < 32; ++u) {
            float v = sWA[tid][u];
            b3 = fmaxf(b3, fminf(b2, v));
            b2 = fmaxf(b2, fminf(b1, v));
            b1 = fmaxf(b1, fminf(b0, v));
            b0 = fmaxf(b0, v);
        }
        sTau[tid] = b3;                  // exact pool-4th
    }
    __syncthreads();
    tauv0 = sTau[qg*4 + 0]; tauv1 = sTau[qg*4 + 1];
    tauv2 = sTau[qg*4 + 2]; tauv3 = sTau[qg*4 + 3];
    float cmin = fminf(fminf(tauv0, tauv1), fminf(tauv2, tauv3));

    // ---- phase B: gated append scan over all 10 chunks (double-buffered) ----
    BSCAN(0, 0)
    __syncthreads();
    STAGE(0, 2) BSCAN(1, 1*CHK2)
    __syncthreads();
    STAGE(1, 3) BSCAN(0, 2*CHK2)
    __syncthreads();
    STAGE(0, 4) BSCAN(1, 3*CHK2)
    __syncthreads();
    STAGE(1, 5) BSCAN(0, 4*CHK2)
    __syncthreads();
    STAGE(0, 6) BSCAN(1, 5*CHK2)
    __syncthreads();
    STAGE(1, 7) BSCAN(0, 6*CHK2)
    __syncthreads();
    STAGE(0, 8) BSCAN(1, 7*CHK2)
    __syncthreads();
    STAGE(1, 9) BSCAN(0, 8*CHK2)
    __syncthreads();
    BSCAN(1, 9*CHK2)
    __syncthreads();

    // ---- phase C: exact lex rank-select (16 threads/query) ----
    {
        int qi = tid >> 4;
        int sl = tid & 15;
        int C = sCnt[qi]; if (C > CAP2) C = CAP2;
        for (int i = sl; i < C; i += 16) {
            float ei = sCE[qi][i]; int ii = sCI[qi][i];
            int rank = 0;
            for (int j = 0; j < C; ++j) {
                float ej = sCE[qi][j]; int ij = sCI[qi][j];
                rank += ((ej > ei) || (ej == ei && ij < ii)) ? 1 : 0;
            }
            if (rank < KSC) sTop[qi][rank] = ii;
        }
    }
    __syncthreads();
    if (tid < QPB) {
        int q = qbase + tid;
        float4 f4 = ((const float4*)(ws + OFF_FP))[q];
        float4 n0 = pts[sTop[tid][0]], n1 = pts[sTop[tid][1]];
        float4 n2 = pts[sTop[tid][2]], n3 = pts[sTop[tid][3]];
        float gx = 0.f, gy = 0.f, gz = 0.f;
        gx += n0.x - f4.x; gy += n0.y - f4.y; gz += n0.z - f4.z;
        gx += n1.x - f4.x; gy += n1.y - f4.y; gz += n1.z - f4.z;
        gx += n2.x - f4.x; gy += n2.y - f4.y; gz += n2.z - f4.z;
        gx += n3.x - f4.x; gy += n3.y - f4.y; gz += n3.z - f4.z;
        float* gsp = ws + OFF_GS + (size_t)q*4;
        gsp[0] = gx*0.25f; gsp[1] = gy*0.25f; gsp[2] = gz*0.25f;
    }
}

// ---------------- Stage 5: score MLP + loss — 4-wave j-split, packed g4 --------
__global__ __launch_bounds__(256) void k_mlp(const float* __restrict__ Ws1,
                                             const float* __restrict__ Ws2, const float* __restrict__ bs2,
                                             const float* __restrict__ Ws3, const float* __restrict__ bs3,
                                             float* __restrict__ ws) {
    __shared__ float4 sG[2][128];        // (zp_i, W1[0][i], W1[1][i], W1[2][i])
    __shared__ float4 sW2[128][16];
    __shared__ float  sB2[64];
    __shared__ float  sW3[64][3];
    __shared__ float  sB3[3];
    __shared__ float  sE[3][4][64];
    int tid = threadIdx.x;
    int w = tid >> 6, lane = tid & 63;
    for (int u = tid; u < 2048; u += 256) ((float4*)sW2)[u] = ((const float4*)Ws2)[u];
    if (tid < 64) sB2[tid] = bs2[tid];
    if (tid < 192) ((float*)sW3)[tid] = Ws3[tid];
    if (tid < 3) sB3[tid] = bs3[tid];
    {
        int grp = tid >> 7, i = tid & 127;
        sG[grp][i] = make_float4(ws[OFF_ZP + (blockIdx.x*2 + grp)*ZZ + i],
                                 Ws1[i], Ws1[128 + i], Ws1[256 + i]);
    }
    __syncthreads();

    int g = blockIdx.x*64 + lane;
    float4 f4 = ((const float4*)(ws + OFF_FP))[g];
    float4 fo = ((const float4*)(ws + OFF_FO))[g >> 5];
    float x0 = f4.x - fo.x, x1 = f4.y - fo.y, x2 = f4.z - fo.z;
    int grp = lane >> 5;

    float4 a[4];
    #pragma unroll
    for (int qq = 0; qq < 4; ++qq) a[qq] = make_float4(0.f, 0.f, 0.f, 0.f);
    for (int i = 0; i < 128; ++i) {
        float4 gv = sG[grp][i];
        float h1 = fmaf(x2, gv.w, fmaf(x1, gv.z, fmaf(x0, gv.y, gv.x)));
        h1 = fmaxf(h1, 0.0f);
        #pragma unroll
        for (int qq = 0; qq < 4; ++qq) {
            float4 wv = sW2[i][w*4 + qq];
            a[qq].x = fmaf(h1, wv.x, a[qq].x);
            a[qq].y = fmaf(h1, wv.y, a[qq].y);
            a[qq].z = fmaf(h1, wv.z, a[qq].z);
            a[qq].w = fmaf(h1, wv.w, a[qq].w);
        }
    }
    float p0 = 0.f, p1 = 0.f, p2 = 0.f;
    #pragma unroll
    for (int qq = 0; qq < 4; ++qq) {
        float av[4] = {a[qq].x, a[qq].y, a[qq].z, a[qq].w};
        #pragma unroll
        for (int cc = 0; cc < 4; ++cc) {
            int j = w*16 + qq*4 + cc;
            float h2 = fmaxf(av[cc] + sB2[j], 0.0f);
            p0 = fmaf(h2, sW3[j][0], p0);
            p1 = fmaf(h2, sW3[j][1], p1);
            p2 = fmaf(h2, sW3[j][2], p2);
        }
    }
    sE[0][w][lane] = p0; sE[1][w][lane] = p1; sE[2][w][lane] = p2;
    __syncthreads();
    if (w == 0) {
        float ee0 = ((sE[0][0][lane] + sE[0][1][lane]) + sE[0][2][lane]) + sE[0][3][lane] + sB3[0];
        float ee1 = ((sE[1][0][lane] + sE[1][1][lane]) + sE[1][2][lane]) + sE[1][3][lane] + sB3[1];
        float ee2 = ((sE[2][0][lane] + sE[2][1][lane]) + sE[2][2][lane]) + sE[2][3][lane] + sB3[2];
        const float* gsp = ws + OFF_GS + (size_t)g*4;
        float d0 = ee0 - gsp[0], d1 = ee1 - gsp[1], d2 = ee2 - gsp[2];
        float t = ((d0*d0 + d1*d1) + d2*d2) * 100.0f;
        for (int off = 32; off > 0; off >>= 1) t += __shfl_down(t, off);
        if (lane == 0) atomicAdd(ws + OFF_AC, t);
    }
}

// ---------------- Stage 6: finalize --------------------------------------------
__global__ void k_fin(const float* __restrict__ ws, float* __restrict__ out) {
    if (threadIdx.x == 0 && blockIdx.x == 0)
        out[0] = ws[OFF_AC] * (1.0f / 32768.0f);
}

extern "C" void kernel_launch(void* const* d_in, const int* in_sizes, int n_in,
                              void* d_out, int out_size, void* d_ws, size_t ws_size,
                              hipStream_t stream) {
    const float* noisy = (const float*)d_in[0];
    const float* clean = (const float*)d_in[1];
    const int*   sidx  = (const int*)  d_in[2];
    const float* Wf1 = (const float*)d_in[3];
    const float* bf1 = (const float*)d_in[4];
    const float* Wf2 = (const float*)d_in[5];
    const float* bf2 = (const float*)d_in[6];
    const float* Ws1 = (const float*)d_in[7];
    const float* bs1 = (const float*)d_in[8];
    const float* Ws2 = (const float*)d_in[9];
    const float* bs2 = (const float*)d_in[10];
    const float* Ws3 = (const float*)d_in[11];
    const float* bs3 = (const float*)d_in[12];
    float* ws  = (float*)d_ws;
    float* out = (float*)d_out;

    k_pack<<<(BB*NN + BB*MM + 255)/256, 256, 0, stream>>>(noisy, clean, ws);
    k_feat<<<(BB*PP*64)/256, 256, 0, stream>>>(sidx, Wf1, bf1, Wf2, bf2, Ws1, bs1, ws);
    k_knn1<<<BB*PP, 256, 0, stream>>>(sidx, ws);
    k_knn2<<<(BB*PP*KS)/QPB, 512, 0, stream>>>(ws);
    k_mlp<<<(BB*PP*KS)/64, 256, 0, stream>>>(Ws1, Ws2, bs2, Ws3, bs3, ws);
    k_fin<<<1, 64, 0, stream>>>(ws, out);
}